// Round 3
// baseline (1500.955 us; speedup 1.0000x reference)
//
#include <hip/hip_runtime.h>
#include <hip/hip_bf16.h>
#include <stdint.h>

#define HFR 128
#define HTO 128
#define LDF 132          // fp32 LDS tile leading dim (128+4, 16B-aligned rows)
#define TILE 64          // dst nodes per mega block

typedef short short8 __attribute__((ext_vector_type(8)));   // 8 bf16 = 4 VGPRs
typedef float f32x4  __attribute__((ext_vector_type(4)));   // MFMA C/D
typedef unsigned long long u64;
typedef unsigned int uint;

static __device__ __forceinline__ unsigned short f2bf(float x) {
    __hip_bfloat16 h = __float2bfloat16(x);
    return *reinterpret_cast<unsigned short*>(&h);
}
static __device__ __forceinline__ float bflo(uint x) {
    return __uint_as_float(x << 16);           // low bf16 -> f32
}
static __device__ __forceinline__ float bfhi(uint x) {
    return __uint_as_float(x & 0xffff0000u);   // high bf16 -> f32
}

// ---------------------------------------------------------------------------
// prep: fused {zero row-histogram | nodes fp32->bf16 | weights -> MFMA frags}
// block ranges: [0,ZB) zero, [ZB,ZB+CB) conv_nodes, [ZB+CB, +64) conv_weights
// ---------------------------------------------------------------------------
__global__ __launch_bounds__(256)
void prep(const float* __restrict__ nodes, const float* __restrict__ weights,
          unsigned short* __restrict__ ndbf, short8* __restrict__ Wf,
          int* __restrict__ cnt, int NR, int N, int ZB, int CB) {
    int b = blockIdx.x;
    int t = threadIdx.x;
    if (b < ZB) {                       // zero cnt[0..NR)
        int i = b * 256 + t;
        if (i < NR) cnt[i] = 0;
        return;
    }
    b -= ZB;
    if (b < CB) {                       // nodes fp32 -> bf16, row-major
        int id = b * 256 + t;           // id over N*16 (8 feats each)
        if (id < N * 16) {
            int n  = id >> 4;
            int k8 = id & 15;
            const float4* s = reinterpret_cast<const float4*>(nodes);
            float4 v0 = s[(size_t)n * 32 + k8 * 2];
            float4 v1 = s[(size_t)n * 32 + k8 * 2 + 1];
            short8 sv;
            sv[0] = f2bf(v0.x); sv[1] = f2bf(v0.y); sv[2] = f2bf(v0.z); sv[3] = f2bf(v0.w);
            sv[4] = f2bf(v1.x); sv[5] = f2bf(v1.y); sv[6] = f2bf(v1.z); sv[7] = f2bf(v1.w);
            *reinterpret_cast<short8*>(&ndbf[(size_t)n * HFR + k8 * 8]) = sv;
        }
        return;
    }
    b -= CB;                            // weights -> fragment layout (16384 ids)
    int id = b * 256 + t;
    int lane = id & 63;
    int kk   = (id >> 6) & 3;
    int j    = (id >> 8) & 7;
    int r    = id >> 11;
    int m = lane & 15, q = lane >> 4;
    const float* src = weights + (((size_t)r * HFR) + j * 16 + m) * HTO + kk * 32 + q * 8;
    short8 sv;
#pragma unroll
    for (int e = 0; e < 8; ++e) sv[e] = f2bf(src[e]);
    Wf[((r * 4 + kk) * 8 + j) * 64 + lane] = sv;
}

// ---------------------------------------------------------------------------
// histogram over full row id (r*N+dst): 800K bins, avg 2 edges/bin
// ---------------------------------------------------------------------------
__global__ __launch_bounds__(256)
void count_kernel(const int* __restrict__ rows, int* __restrict__ cnt, int nnz) {
    int e = blockIdx.x * 256 + threadIdx.x;
    if (e >= nnz) return;
    atomicAdd(&cnt[rows[e]], 1);
}

// ---------------------------------------------------------------------------
// hierarchical exclusive scan (3 levels for 800K)
// ---------------------------------------------------------------------------
__global__ __launch_bounds__(256)
void scan_reduce(const int* __restrict__ cnt, int* __restrict__ bsum, int N) {
    __shared__ int s[256];
    int t = threadIdx.x;
    int i = blockIdx.x * 256 + t;
    s[t] = (i < N) ? cnt[i] : 0;
    __syncthreads();
    for (int off = 128; off > 0; off >>= 1) {
        if (t < off) s[t] += s[t + off];
        __syncthreads();
    }
    if (t == 0) bsum[blockIdx.x] = s[0];
}

__global__ __launch_bounds__(1024)
void scan_block(int* __restrict__ bsum, int nb) {
    __shared__ int s[1024];
    int t = threadIdx.x;
    s[t] = (t < nb) ? bsum[t] : 0;
    __syncthreads();
    for (int off = 1; off < 1024; off <<= 1) {
        int o = (t >= off) ? s[t - off] : 0;
        __syncthreads();
        s[t] += o;
        __syncthreads();
    }
    if (t < nb) bsum[t] = (t == 0) ? 0 : s[t - 1];
}

__global__ __launch_bounds__(256)
void scan_final(int* __restrict__ cnt, const int* __restrict__ bsum, int N) {
    __shared__ int s[256];
    int t = threadIdx.x;
    int i = blockIdx.x * 256 + t;
    int v = (i < N) ? cnt[i] : 0;
    s[t] = v;
    __syncthreads();
    for (int off = 1; off < 256; off <<= 1) {
        int o = (t >= off) ? s[t - off] : 0;
        __syncthreads();
        s[t] += o;
        __syncthreads();
    }
    int ex = ((t == 0) ? 0 : s[t - 1]) + bsum[blockIdx.x];
    if (i < N) cnt[i] = ex;     // cnt becomes the segment-start cursor
}

// ---------------------------------------------------------------------------
// counting-sort placement: sorted[] ordered by row id (r*N+dst).
// record: [val f32 (hi 32)] [dst&63 (bits 17..22)] [col (bits 0..16)]
// ---------------------------------------------------------------------------
__global__ __launch_bounds__(256)
void place_kernel(const int* __restrict__ rows, const int* __restrict__ cols,
                  const float* __restrict__ vals,
                  int* __restrict__ cursor, u64* __restrict__ sorted,
                  int N, int nnz) {
    int e = blockIdx.x * 256 + threadIdx.x;
    if (e >= nnz) return;
    int row = rows[e];
    int r   = row / N;
    int dst = row - r * N;
    int pos = atomicAdd(&cursor[row], 1);
    uint lo = (uint)cols[e] | ((uint)(dst & (TILE - 1)) << 17);
    sorted[pos] = ((u64)__float_as_uint(vals[e]) << 32) | (u64)lo;
}

// ---------------------------------------------------------------------------
// MEGA kernel: aggregate-then-GEMM, H eliminated.
// Each block owns TILE=64 dst nodes. Per relation r:
//   zero fp32 LDS tile [64][LDF] -> aggregate this block's (contiguous) edge
//   segment with LDS float atomics (per-edge random 256B reads hit the
//   25.6MB bf16 node array = L2/L3-hot) -> convert fragments -> MFMA with
//   pre-swizzled W_r, accumulating acc across ALL relations in registers.
// Epilogue once: relu + fp32 out (full-sector stores).
// MFMA config identical to the numerically-verified round-1 kernel:
//   a = agg rows, b = W rows; D[row=quad*4+reg <-> node][col=m <-> feat],
//   feature index = j*16+m.
// ---------------------------------------------------------------------------
__global__ __launch_bounds__(256, 4)
void mega(const unsigned short* __restrict__ ndbf,
          const short8* __restrict__ Wf,
          const u64* __restrict__ sorted,
          const int* __restrict__ cursor,
          float* __restrict__ out, int N, int R) {
    __shared__ float tile[TILE * LDF];          // 33792 B -> 4 blocks/CU

    const int t    = threadIdx.x;
    const int lane = t & 63;
    const int w    = t >> 6;
    const int m    = lane & 15;
    const int quad = lane >> 4;
    const int q8   = quad * 8;
    const int w16  = w * 16;
    const int n0   = blockIdx.x * TILE;
    const int nend = min(n0 + TILE, N);

    const uint* nd32 = reinterpret_cast<const uint*>(ndbf);
    float4* t4 = reinterpret_cast<float4*>(tile);

    f32x4 acc[8];
#pragma unroll
    for (int j = 0; j < 8; ++j) acc[j] = (f32x4)(0.f);

#define VAL(q)  __uint_as_float((uint)((q) >> 32))
#define EDGE(q, x) {                                                         \
        float v  = VAL(q);                                                   \
        int   dl = (int)(((uint)(q) >> 17) & (TILE - 1));                    \
        atomicAdd(&tile[dl * LDF + 2 * lane],     bflo(x) * v);              \
        atomicAdd(&tile[dl * LDF + 2 * lane + 1], bfhi(x) * v);              \
    }
#define NDROW(q) nd32[((size_t)((uint)(q) & 0x1FFFF)) * 64 + lane]

    for (int r = 0; r < R; ++r) {
        // ---- zero tile ----
#pragma unroll 4
        for (int i = t; i < TILE * LDF / 4; i += 256)
            t4[i] = make_float4(0.f, 0.f, 0.f, 0.f);
        __syncthreads();

        // ---- aggregate this block's edges for relation r ----
        int rowid0 = r * N + n0;
        int e0 = (rowid0 == 0) ? 0 : cursor[rowid0 - 1];
        int e1 = cursor[r * N + nend - 1];
        int cntE  = e1 - e0;
        int chunk = (cntE + 3) >> 2;
        int ce0 = e0 + w * chunk;
        int ce1 = min(ce0 + chunk, e1);
        int e = ce0;
        for (; e + 8 <= ce1; e += 8) {
            const u64* p = sorted + __builtin_amdgcn_readfirstlane(e);
            u64 q0 = p[0], q1 = p[1], q2 = p[2], q3 = p[3];
            u64 q4 = p[4], q5 = p[5], q6 = p[6], q7 = p[7];
            uint x0 = NDROW(q0);
            uint x1 = NDROW(q1);
            uint x2 = NDROW(q2);
            uint x3 = NDROW(q3);
            uint x4 = NDROW(q4);
            uint x5 = NDROW(q5);
            uint x6 = NDROW(q6);
            uint x7 = NDROW(q7);
            EDGE(q0, x0) EDGE(q1, x1) EDGE(q2, x2) EDGE(q3, x3)
            EDGE(q4, x4) EDGE(q5, x5) EDGE(q6, x6) EDGE(q7, x7)
        }
        for (; e < ce1; ++e) {
            u64 q0 = sorted[e];
            uint x0 = NDROW(q0);
            EDGE(q0, x0)
        }
        __syncthreads();

        // ---- GEMM: acc += W_r * agg_tile ----
        const short8* wr = Wf + (size_t)r * 2048 + lane;
#pragma unroll
        for (int kk = 0; kk < 4; ++kk) {
            const float4* fp = reinterpret_cast<const float4*>(
                &tile[(w16 + m) * LDF + kk * 32 + q8]);
            float4 f0 = fp[0], f1 = fp[1];
            short8 a;
            a[0] = f2bf(f0.x); a[1] = f2bf(f0.y); a[2] = f2bf(f0.z); a[3] = f2bf(f0.w);
            a[4] = f2bf(f1.x); a[5] = f2bf(f1.y); a[6] = f2bf(f1.z); a[7] = f2bf(f1.w);
#pragma unroll
            for (int j = 0; j < 8; ++j)
                acc[j] = __builtin_amdgcn_mfma_f32_16x16x32_bf16(a, wr[kk * 512 + j * 64],
                                                                 acc[j], 0, 0, 0);
        }
        __syncthreads();   // tile reads done before next relation's zeroing
    }
#undef NDROW
#undef EDGE
#undef VAL

    // ---- epilogue: relu + store fp32 out ----
#pragma unroll
    for (int reg = 0; reg < 4; ++reg) {
        int n = n0 + w16 + quad * 4 + reg;
        if (n < N) {
            float* dst = out + (size_t)n * HTO + m;
#pragma unroll
            for (int j = 0; j < 8; ++j)
                dst[j * 16] = fmaxf(acc[j][reg], 0.f);
        }
    }
}

// ---------------------------------------------------------------------------
extern "C" void kernel_launch(void* const* d_in, const int* in_sizes, int n_in,
                              void* d_out, int out_size, void* d_ws, size_t ws_size,
                              hipStream_t stream) {
    const float* nodes   = (const float*)d_in[0];   // [N, HFR] fp32
    const int*   indices = (const int*)d_in[1];     // [2, NNZ] int32
    const float* vals    = (const float*)d_in[2];   // [NNZ] fp32
    const float* weights = (const float*)d_in[3];   // [R, HFR, HTO] fp32

    const int N   = in_sizes[0] / HFR;
    const int nnz = in_sizes[1] / 2;
    const int R   = in_sizes[3] / (HFR * HTO);
    const int NR  = N * R;

    const int* rows = indices;
    const int* cols = indices + nnz;

    // Workspace layout (~42 MB):
    //   ndbf   : [N, HFR] bf16      (25.6 MB)
    //   sorted : [nnz] u64          (12.8 MB)
    //   cnt    : [N*R] int          (3.2 MB)
    //   b1     : [ceil(NR/256)] int (12.5 KB)
    //   b2     : [1024] int
    //   Wf     : [R*4*8*64] short8  (256 KB)
    char* ws = (char*)d_ws;
    unsigned short* ndbf = (unsigned short*)ws;
    size_t off = (size_t)N * HFR * sizeof(unsigned short);
    u64* sorted = (u64*)(ws + off);
    off += (size_t)nnz * sizeof(u64);
    int* cnt = (int*)(ws + off);
    off += (size_t)NR * sizeof(int);
    const int NB1 = (NR + 255) / 256;          // 3125
    int* b1 = (int*)(ws + off);
    off += (size_t)NB1 * sizeof(int);
    int* b2 = (int*)(ws + off);
    off += 1024 * sizeof(int);
    short8* Wf = (short8*)(ws + off);

    float* out = (float*)d_out;

    const int ZB  = NB1;                        // zero blocks
    const int CB  = (N * 16 + 255) / 256;       // conv_nodes blocks (6250)
    const int WB  = (R * 4 * 8 * 64) / 256;     // conv_weights blocks (64)
    const int EB  = (nnz + 255) / 256;          // edge-parallel blocks (6250)
    const int NB2 = (NB1 + 255) / 256;          // 13
    const int MB  = (N + TILE - 1) / TILE;      // mega blocks (1563)

    // 1) fused prep: zero cnt | nodes->bf16 | weights->frags
    prep<<<ZB + CB + WB, 256, 0, stream>>>(nodes, weights, ndbf, Wf, cnt, NR, N, ZB, CB);
    // 2) row histogram
    count_kernel<<<EB, 256, 0, stream>>>(rows, cnt, nnz);
    // 3) 3-level exclusive scan of 800K counters
    scan_reduce<<<NB1, 256, 0, stream>>>(cnt, b1, NR);
    scan_reduce<<<NB2, 256, 0, stream>>>(b1, b2, NB1);
    scan_block<<<1, 1024, 0, stream>>>(b2, NB2);
    scan_final<<<NB2, 256, 0, stream>>>(b1, b2, NB1);
    scan_final<<<NB1, 256, 0, stream>>>(cnt, b1, NR);
    // 4) counting-sort placement (sorted by row id)
    place_kernel<<<EB, 256, 0, stream>>>(rows, cols, vals, cnt, sorted, N, nnz);
    // 5) aggregate + GEMM + relu (H eliminated)
    mega<<<MB, 256, 0, stream>>>(ndbf, Wf, sorted, cnt, out, N, R);
}

// Round 4
// 477.926 us; speedup vs baseline: 3.1406x; 3.1406x over previous
//
#include <hip/hip_runtime.h>
#include <hip/hip_bf16.h>
#include <stdint.h>

#define HFR 128
#define HTO 128

typedef short short8 __attribute__((ext_vector_type(8)));   // 8 bf16 = 4 VGPRs
typedef float f32x4  __attribute__((ext_vector_type(4)));   // MFMA C/D
typedef unsigned long long u64;
typedef unsigned int uint;

static __device__ __forceinline__ unsigned short f2bf(float x) {
    __hip_bfloat16 h = __float2bfloat16(x);
    return *reinterpret_cast<unsigned short*>(&h);
}
static __device__ __forceinline__ float bflo(uint x) {
    return __uint_as_float(x << 16);           // low bf16 -> f32
}
static __device__ __forceinline__ float bfhi(uint x) {
    return __uint_as_float(x & 0xffff0000u);   // high bf16 -> f32
}

// ---------------------------------------------------------------------------
// zero the (r,dst) histogram
// ---------------------------------------------------------------------------
__global__ __launch_bounds__(256) void zero_i32(int* __restrict__ p, int n) {
    int i = blockIdx.x * 256 + threadIdx.x;
    if (i < n) p[i] = 0;
}

// ---------------------------------------------------------------------------
// fused: {row histogram | nodes fp32->bf16 | weights -> MFMA A-frag layout}
// block ranges: [0,EB) count, [EB,EB+CB) conv_nodes, [EB+CB, +WB) conv_weights
// (count's atomic latency hides the 38MB of conversion traffic)
// ---------------------------------------------------------------------------
__global__ __launch_bounds__(256)
void prep2(const int* __restrict__ rows, int* __restrict__ cnt, int nnz,
           const float* __restrict__ nodes, unsigned short* __restrict__ ndbf, int N,
           const float* __restrict__ weights, short8* __restrict__ Wf,
           int EB, int CB) {
    int b = blockIdx.x;
    int t = threadIdx.x;
    if (b < EB) {                       // histogram over row id (r*N+dst)
        int e = b * 256 + t;
        if (e < nnz) atomicAdd(&cnt[rows[e]], 1);
        return;
    }
    b -= EB;
    if (b < CB) {                       // nodes fp32 -> bf16, row-major
        int id = b * 256 + t;           // id over N*16 (8 feats each)
        if (id < N * 16) {
            int n  = id >> 4;
            int k8 = id & 15;
            const float4* s = reinterpret_cast<const float4*>(nodes);
            float4 v0 = s[(size_t)n * 32 + k8 * 2];
            float4 v1 = s[(size_t)n * 32 + k8 * 2 + 1];
            short8 sv;
            sv[0] = f2bf(v0.x); sv[1] = f2bf(v0.y); sv[2] = f2bf(v0.z); sv[3] = f2bf(v0.w);
            sv[4] = f2bf(v1.x); sv[5] = f2bf(v1.y); sv[6] = f2bf(v1.z); sv[7] = f2bf(v1.w);
            *reinterpret_cast<short8*>(&ndbf[(size_t)n * HFR + k8 * 8]) = sv;
        }
        return;
    }
    b -= CB;                            // weights -> fragment layout (16384 ids)
    int id = b * 256 + t;
    int lane = id & 63;
    int kk   = (id >> 6) & 3;
    int j    = (id >> 8) & 7;
    int r    = id >> 11;
    int m = lane & 15, q = lane >> 4;
    const float* src = weights + (((size_t)r * HFR) + j * 16 + m) * HTO + kk * 32 + q * 8;
    short8 sv;
#pragma unroll
    for (int e = 0; e < 8; ++e) sv[e] = f2bf(src[e]);
    Wf[((r * 4 + kk) * 8 + j) * 64 + lane] = sv;
}

// ---------------------------------------------------------------------------
// hierarchical exclusive scan (3 levels for 800K bins) — proven round 3
// ---------------------------------------------------------------------------
__global__ __launch_bounds__(256)
void scan_reduce(const int* __restrict__ cnt, int* __restrict__ bsum, int N) {
    __shared__ int s[256];
    int t = threadIdx.x;
    int i = blockIdx.x * 256 + t;
    s[t] = (i < N) ? cnt[i] : 0;
    __syncthreads();
    for (int off = 128; off > 0; off >>= 1) {
        if (t < off) s[t] += s[t + off];
        __syncthreads();
    }
    if (t == 0) bsum[blockIdx.x] = s[0];
}

__global__ __launch_bounds__(1024)
void scan_block(int* __restrict__ bsum, int nb) {
    __shared__ int s[1024];
    int t = threadIdx.x;
    s[t] = (t < nb) ? bsum[t] : 0;
    __syncthreads();
    for (int off = 1; off < 1024; off <<= 1) {
        int o = (t >= off) ? s[t - off] : 0;
        __syncthreads();
        s[t] += o;
        __syncthreads();
    }
    if (t < nb) bsum[t] = (t == 0) ? 0 : s[t - 1];
}

__global__ __launch_bounds__(256)
void scan_final(int* __restrict__ cnt, const int* __restrict__ bsum, int N) {
    __shared__ int s[256];
    int t = threadIdx.x;
    int i = blockIdx.x * 256 + t;
    int v = (i < N) ? cnt[i] : 0;
    s[t] = v;
    __syncthreads();
    for (int off = 1; off < 256; off <<= 1) {
        int o = (t >= off) ? s[t - off] : 0;
        __syncthreads();
        s[t] += o;
        __syncthreads();
    }
    int ex = ((t == 0) ? 0 : s[t - 1]) + bsum[blockIdx.x];
    if (i < N) cnt[i] = ex;     // cnt becomes the segment-start cursor
}

// ---------------------------------------------------------------------------
// counting-sort placement: sorted[] ordered by row id (r*N+dst).
// record: [val f32 (hi 32)] [col (lo 32)] — no div needed anymore.
// ---------------------------------------------------------------------------
__global__ __launch_bounds__(256)
void place_kernel(const int* __restrict__ rows, const int* __restrict__ cols,
                  const float* __restrict__ vals,
                  int* __restrict__ cursor, u64* __restrict__ sorted, int nnz) {
    int e = blockIdx.x * 256 + threadIdx.x;
    if (e >= nnz) return;
    int row = rows[e];
    int pos = atomicAdd(&cursor[row], 1);
    sorted[pos] = ((u64)__float_as_uint(vals[e]) << 32) | (u64)(uint)cols[e];
}

// ---------------------------------------------------------------------------
// AGG: agg[row=r*N+dst][0..127] = sum_e val * nodes_bf16[col].
// One wave per 4 consecutive row-segments (NR/4 = 200K waves): max TLP,
// zero LDS, zero barriers, ~30 VGPR. Lane l owns feats {2l, 2l+1}.
// Row store: one packed uint per lane = coalesced 256B bf16 row.
// ---------------------------------------------------------------------------
__global__ __launch_bounds__(256)
void agg_kernel(const unsigned short* __restrict__ ndbf,
                const u64* __restrict__ sorted,
                const int* __restrict__ cursor,
                uint* __restrict__ aggp, int NR) {
    int gw   = blockIdx.x * 4 + (threadIdx.x >> 6);
    int lane = threadIdx.x & 63;
    int v0   = gw * 4;                 // NR divisible by 4 here
    if (v0 >= NR) return;

    const uint* nd32 = reinterpret_cast<const uint*>(ndbf);

    int c0 = (v0 == 0) ? 0 : cursor[v0 - 1];
    int c1 = cursor[v0];
    int c2 = cursor[v0 + 1];
    int c3 = cursor[v0 + 2];
    int c4 = cursor[v0 + 3];

#define ROWSEG(E0, E1, V) {                                                  \
        int e = (E0); float a0 = 0.f, a1 = 0.f;                              \
        for (; e + 2 <= (E1); e += 2) {                                      \
            const u64* p = sorted + __builtin_amdgcn_readfirstlane(e);       \
            u64 q0 = p[0], q1 = p[1];                                        \
            uint x0 = nd32[(size_t)(uint)q0 * 64 + lane];                    \
            uint x1 = nd32[(size_t)(uint)q1 * 64 + lane];                    \
            float f0 = __uint_as_float((uint)(q0 >> 32));                    \
            float f1 = __uint_as_float((uint)(q1 >> 32));                    \
            a0 = fmaf(bflo(x0), f0, a0); a1 = fmaf(bfhi(x0), f0, a1);        \
            a0 = fmaf(bflo(x1), f1, a0); a1 = fmaf(bfhi(x1), f1, a1);        \
        }                                                                    \
        if (e < (E1)) {                                                      \
            u64 q0 = sorted[e];                                              \
            uint x0 = nd32[(size_t)(uint)q0 * 64 + lane];                    \
            float f0 = __uint_as_float((uint)(q0 >> 32));                    \
            a0 = fmaf(bflo(x0), f0, a0); a1 = fmaf(bfhi(x0), f0, a1);        \
        }                                                                    \
        aggp[(size_t)(V) * 64 + lane] = ((uint)f2bf(a1) << 16) | (uint)f2bf(a0); \
    }

    ROWSEG(c0, c1, v0)
    ROWSEG(c1, c2, v0 + 1)
    ROWSEG(c2, c3, v0 + 2)
    ROWSEG(c3, c4, v0 + 3)
#undef ROWSEG
}

// ---------------------------------------------------------------------------
// GEMM: out[n] = relu( sum_r W_r * agg[r*N+n] ), all in registers across r.
// Block = 128 nodes, 4 waves x 32 nodes (2 node-sets -> A-frags reused 2x,
// halving L2 A-traffic). Swapped operands (A=W, B=agg rows), verified in
// round 2: D[row=feat j*16+quad*4+reg][col=node m] -> lane's 4 acc regs are
// CONSECUTIVE feats -> direct float4 stores (64B segments per node row).
// ---------------------------------------------------------------------------
__global__ __launch_bounds__(256)
void gemm_kernel(const uint* __restrict__ aggp, const short8* __restrict__ Wf,
                 float* __restrict__ out, int N, int R) {
    const int t    = threadIdx.x;
    const int lane = t & 63;
    const int w    = t >> 6;
    const int m    = lane & 15;
    const int quad = lane >> 4;
    const int nb   = blockIdx.x * 128 + w * 32;   // wave's 32-node base

    f32x4 acc[2][8];
#pragma unroll
    for (int s = 0; s < 2; ++s)
#pragma unroll
        for (int j = 0; j < 8; ++j) acc[s][j] = (f32x4)(0.f);

    for (int r = 0; r < R; ++r) {
        short8 b[2][4];
#pragma unroll
        for (int s = 0; s < 2; ++s) {
            int n = nb + s * 16 + m;
            if (n < N) {
                const short8* rowp = reinterpret_cast<const short8*>(
                    aggp + ((size_t)r * N + n) * 64);
#pragma unroll
                for (int kk = 0; kk < 4; ++kk) b[s][kk] = rowp[kk * 4 + quad];
            } else {
#pragma unroll
                for (int kk = 0; kk < 4; ++kk) b[s][kk] = (short8)(short)0;
            }
        }
        const short8* wr = Wf + (size_t)r * 2048 + lane;
#pragma unroll
        for (int kk = 0; kk < 4; ++kk)
#pragma unroll
            for (int j = 0; j < 8; ++j) {
                short8 aw = wr[kk * 512 + j * 64];
                acc[0][j] = __builtin_amdgcn_mfma_f32_16x16x32_bf16(aw, b[0][kk], acc[0][j], 0, 0, 0);
                acc[1][j] = __builtin_amdgcn_mfma_f32_16x16x32_bf16(aw, b[1][kk], acc[1][j], 0, 0, 0);
            }
    }

#pragma unroll
    for (int s = 0; s < 2; ++s) {
        int n = nb + s * 16 + m;
        if (n < N) {
#pragma unroll
            for (int j = 0; j < 8; ++j) {
                float4 o;
                o.x = fmaxf(acc[s][j][0], 0.f);
                o.y = fmaxf(acc[s][j][1], 0.f);
                o.z = fmaxf(acc[s][j][2], 0.f);
                o.w = fmaxf(acc[s][j][3], 0.f);
                *reinterpret_cast<float4*>(out + (size_t)n * HTO + j * 16 + quad * 4) = o;
            }
        }
    }
}

// ---------------------------------------------------------------------------
extern "C" void kernel_launch(void* const* d_in, const int* in_sizes, int n_in,
                              void* d_out, int out_size, void* d_ws, size_t ws_size,
                              hipStream_t stream) {
    const float* nodes   = (const float*)d_in[0];   // [N, HFR] fp32
    const int*   indices = (const int*)d_in[1];     // [2, NNZ] int32
    const float* vals    = (const float*)d_in[2];   // [NNZ] fp32
    const float* weights = (const float*)d_in[3];   // [R, HFR, HTO] fp32

    const int N   = in_sizes[0] / HFR;
    const int nnz = in_sizes[1] / 2;
    const int R   = in_sizes[3] / (HFR * HTO);
    const int NR  = N * R;

    const int* rows = indices;
    const int* cols = indices + nnz;

    // ws (217.9 MB): aggp [NR,128] bf16 | sorted [nnz] u64 | Wf 256KB
    char* ws = (char*)d_ws;
    uint* aggp = (uint*)ws;                          // NR * 64 uints
    size_t off = (size_t)NR * 64 * sizeof(uint);
    u64* sorted = (u64*)(ws + off);
    off += (size_t)nnz * sizeof(u64);
    short8* Wf = (short8*)(ws + off);

    // d_out scratch (28.8 MB, all dead before gemm writes out):
    //   ndbf [N,HFR] bf16 | cnt [NR] int | b1 | b2
    char* ob = (char*)d_out;
    unsigned short* ndbf = (unsigned short*)ob;
    size_t ooff = (size_t)N * HFR * sizeof(unsigned short);
    int* cnt = (int*)(ob + ooff);
    ooff += (size_t)NR * sizeof(int);
    const int NB1 = (NR + 255) / 256;                // 3125
    int* b1 = (int*)(ob + ooff);
    ooff += (size_t)NB1 * sizeof(int);
    int* b2 = (int*)(ob + ooff);

    float* out = (float*)d_out;

    const int EB  = (nnz + 255) / 256;               // 6250
    const int CB  = (N * 16 + 255) / 256;            // 6250
    const int WB  = (R * 4 * 8 * 64) / 256;          // 64
    const int NB2 = (NB1 + 255) / 256;               // 13
    const int AB  = (NR / 4 + 3) / 4;                // 50000 agg blocks
    const int GB  = (N + 127) / 128;                 // 782 gemm blocks

    // 1) zero histogram
    zero_i32<<<NB1, 256, 0, stream>>>(cnt, NR);
    // 2) fused: row histogram | nodes->bf16 | weights->frags
    prep2<<<EB + CB + WB, 256, 0, stream>>>(rows, cnt, nnz, nodes, ndbf, N,
                                            weights, Wf, EB, CB);
    // 3) 3-level exclusive scan of 800K counters
    scan_reduce<<<NB1, 256, 0, stream>>>(cnt, b1, NR);
    scan_reduce<<<NB2, 256, 0, stream>>>(b1, b2, NB1);
    scan_block<<<1, 1024, 0, stream>>>(b2, NB2);
    scan_final<<<NB2, 256, 0, stream>>>(b1, b2, NB1);
    scan_final<<<NB1, 256, 0, stream>>>(cnt, b1, NR);
    // 4) counting-sort placement (sorted by row id)
    place_kernel<<<EB, 256, 0, stream>>>(rows, cols, vals, cnt, sorted, nnz);
    // 5) aggregate (high-TLP, barrier-free)
    agg_kernel<<<AB, 256, 0, stream>>>(ndbf, sorted, cnt, aggp, NR);
    // 6) batched GEMM over relations + relu
    gemm_kernel<<<GB, 256, 0, stream>>>(aggp, Wf, out, N, R);
}